// Round 3
// baseline (4995.024 us; speedup 1.0000x reference)
//
#include <hip/hip_runtime.h>
#include <math.h>

#define NB 4
#define NC 256
#define NCI 128
#define NC2 512
#define NPOS 4096

// ---------------- transpose weights: dst[c][o] = src[o][c] ----------------
__global__ void k_transpose(const float* __restrict__ src, float* __restrict__ dst,
                            int rows, int cols) {
  int i = blockIdx.x * 256 + threadIdx.x;
  if (i < rows * cols) {
    int o = i / cols, c = i % cols;
    dst[c * rows + o] = src[i];
  }
}

// ---------------- 1x1 conv over channels ----------------
// in: [B][Cin][N], wt: [Cin][Cout] (pre-transposed).
// POS_MAJOR: out[B][N][Cout]; else out[B][Cout][N] (+ optional residual).
template<bool POS_MAJOR, bool HAS_RES>
__global__ __launch_bounds__(256) void k_conv1x1(
    const float* __restrict__ in, const float* __restrict__ wt,
    float* __restrict__ out, const float* __restrict__ res,
    int Cin, int Cout) {
  __shared__ float xs[32][68];
  __shared__ float wsh[32][132];
  const int tid = threadIdx.x;
  const int tp = tid & 15, to = tid >> 4;
  const int p0 = blockIdx.x * 64, o0 = blockIdx.y * 128, b = blockIdx.z;
  const float* inb = in + (size_t)b * Cin * NPOS + p0;
  float acc[8][4] = {};
  for (int c0 = 0; c0 < Cin; c0 += 32) {
    __syncthreads();
#pragma unroll
    for (int r = 0; r < 8; ++r) {
      int idx = r * 256 + tid; int k = idx >> 6, p = idx & 63;
      xs[k][p] = inb[(size_t)(c0 + k) * NPOS + p];
    }
#pragma unroll
    for (int r = 0; r < 16; ++r) {
      int idx = r * 256 + tid; int k = idx >> 7, o = idx & 127;
      wsh[k][o] = wt[(size_t)(c0 + k) * Cout + o0 + o];
    }
    __syncthreads();
#pragma unroll
    for (int k = 0; k < 32; ++k) {
      float4 xv = *(const float4*)&xs[k][tp * 4];
      float4 w0 = *(const float4*)&wsh[k][to * 8];
      float4 w1 = *(const float4*)&wsh[k][to * 8 + 4];
      float wv[8] = {w0.x, w0.y, w0.z, w0.w, w1.x, w1.y, w1.z, w1.w};
      float xa[4] = {xv.x, xv.y, xv.z, xv.w};
#pragma unroll
      for (int r = 0; r < 8; ++r)
#pragma unroll
        for (int c = 0; c < 4; ++c)
          acc[r][c] += wv[r] * xa[c];
    }
  }
  if (POS_MAJOR) {
    float* ob = out + (size_t)b * NPOS * Cout;
#pragma unroll
    for (int c = 0; c < 4; ++c) {
      int p = p0 + tp * 4 + c;
      float4 v0 = {acc[0][c], acc[1][c], acc[2][c], acc[3][c]};
      float4 v1 = {acc[4][c], acc[5][c], acc[6][c], acc[7][c]};
      *(float4*)&ob[(size_t)p * Cout + o0 + to * 8] = v0;
      *(float4*)&ob[(size_t)p * Cout + o0 + to * 8 + 4] = v1;
    }
  } else {
#pragma unroll
    for (int r = 0; r < 8; ++r) {
      int o = o0 + to * 8 + r;
      size_t oi = (size_t)b * Cout * NPOS + (size_t)o * NPOS + p0 + tp * 4;
      float4 v = {acc[r][0], acc[r][1], acc[r][2], acc[r][3]};
      if (HAS_RES) {
        float4 rv = *(const float4*)&res[oi];
        v.x += rv.x; v.y += rv.y; v.z += rv.z; v.w += rv.w;
      }
      *(float4*)&out[oi] = v;
    }
  }
}

#define DOT_ACC(sa, va, vb) \
  sa.x += va.x * vb.x; sa.y += va.y * vb.y; sa.z += va.z * vb.z; sa.w += va.w * vb.w;

__device__ inline void online_upd(float& m, float& l, float s) {
  float nm = fmaxf(m, s);
  l = l * __expf(m - nm) + __expf(s - nm);
  m = nm;
}

// ---------------- column softmax stats: partial m/l per (b, chunk, j) ----------------
// s[i][j] = dot(theta_row[i], phi_row[j]) over 128. softmax over i (columns j normalized).
__global__ __launch_bounds__(256) void k_stats(
    const float* __restrict__ phi, const float* __restrict__ theta,
    float* __restrict__ pm, float* __restrict__ pl) {
  __shared__ float ph[32][132];
  __shared__ float th[32][132];
  __shared__ float redm[16][32];
  __shared__ float redl[16][32];
  const int tid = threadIdx.x;
  const int tx = tid & 15, ty = tid >> 4;
  const int j0 = blockIdx.x * 32;
  const int chunk = blockIdx.y;   // rows chunk of 2048
  const int b = blockIdx.z;
  const float* phb = phi + (size_t)b * NPOS * NCI;
  const float* thb = theta + (size_t)b * NPOS * NCI;
#pragma unroll
  for (int r = 0; r < 16; ++r) {
    int idx = r * 256 + tid; int row = idx >> 7, k = idx & 127;
    ph[row][k] = phb[(size_t)(j0 + row) * NCI + k];
  }
  float m0 = -INFINITY, m1 = -INFINITY, l0 = 0.f, l1 = 0.f;
  for (int it = 0; it < 64; ++it) {
    int i0 = chunk * 2048 + it * 32;
    __syncthreads();
#pragma unroll
    for (int r = 0; r < 16; ++r) {
      int idx = r * 256 + tid; int row = idx >> 7, k = idx & 127;
      th[row][k] = thb[(size_t)(i0 + row) * NCI + k];
    }
    __syncthreads();
    float4 sa0 = {0, 0, 0, 0}, sa1 = {0, 0, 0, 0}, sa2 = {0, 0, 0, 0}, sa3 = {0, 0, 0, 0};
#pragma unroll
    for (int k4 = 0; k4 < 32; ++k4) {
      float4 ta = *(const float4*)&th[ty][k4 * 4];
      float4 tb = *(const float4*)&th[ty + 16][k4 * 4];
      float4 pa = *(const float4*)&ph[tx][k4 * 4];
      float4 pb = *(const float4*)&ph[tx + 16][k4 * 4];
      DOT_ACC(sa0, ta, pa); DOT_ACC(sa1, ta, pb);
      DOT_ACC(sa2, tb, pa); DOT_ACC(sa3, tb, pb);
    }
    float s00 = sa0.x + sa0.y + sa0.z + sa0.w;
    float s01 = sa1.x + sa1.y + sa1.z + sa1.w;
    float s10 = sa2.x + sa2.y + sa2.z + sa2.w;
    float s11 = sa3.x + sa3.y + sa3.z + sa3.w;
    online_upd(m0, l0, s00); online_upd(m0, l0, s10);   // column j0+tx
    online_upd(m1, l1, s01); online_upd(m1, l1, s11);   // column j0+tx+16
  }
  redm[ty][tx] = m0; redl[ty][tx] = l0;
  redm[ty][tx + 16] = m1; redl[ty][tx + 16] = l1;
  __syncthreads();
  if (tid < 32) {
    int j = tid;
    float mm = -INFINITY;
    for (int t = 0; t < 16; ++t) mm = fmaxf(mm, redm[t][j]);
    float ll = 0.f;
    for (int t = 0; t < 16; ++t) ll += redl[t][j] * __expf(redm[t][j] - mm);
    size_t o = (size_t)(b * 2 + chunk) * NPOS + j0 + j;
    pm[o] = mm; pl[o] = ll;
  }
}

__global__ void k_combine(const float* __restrict__ pm, const float* __restrict__ pl,
                          float* __restrict__ m, float* __restrict__ linv) {
  int i = blockIdx.x * 256 + threadIdx.x;
  if (i >= NB * NPOS) return;
  int b = i / NPOS, j = i % NPOS;
  float m0 = pm[(size_t)(b * 2) * NPOS + j];
  float m1 = pm[(size_t)(b * 2 + 1) * NPOS + j];
  float mm = fmaxf(m0, m1);
  float ll = pl[(size_t)(b * 2) * NPOS + j] * __expf(m0 - mm)
           + pl[(size_t)(b * 2 + 1) * NPOS + j] * __expf(m1 - mm);
  m[i] = mm;
  linv[i] = 1.0f / ll;
}

// ---------------- second pass: out[i][cc] = sum_j exp(s-m[j])*linv[j]*g[cc][j] ----------------
// omid written channel-major [B][C][N]
__global__ __launch_bounds__(256) void k_out(
    const float* __restrict__ phi, const float* __restrict__ theta,
    const float* __restrict__ g, const float* __restrict__ m,
    const float* __restrict__ linv, float* __restrict__ omid) {
  __shared__ float th[32][132];
  __shared__ float pp[32][132];   // phi tile, then reused for P tile [32][32]
  __shared__ float gs[128][36];   // g half-tile [cc][j]
  const int tid = threadIdx.x;
  const int tx = tid & 15, ty = tid >> 4;
  const int i0 = blockIdx.x * 32;
  const int b = blockIdx.y;
  const float* phb = phi + (size_t)b * NPOS * NCI;
  const float* thb = theta + (size_t)b * NPOS * NCI;
  const float* gb = g + (size_t)b * NC * NPOS;
  const float* mb = m + (size_t)b * NPOS;
  const float* lvb = linv + (size_t)b * NPOS;
#pragma unroll
  for (int r = 0; r < 16; ++r) {
    int idx = r * 256 + tid; int row = idx >> 7, k = idx & 127;
    th[row][k] = thb[(size_t)(i0 + row) * NCI + k];
  }
  float acc[2][16] = {};
  for (int jt = 0; jt < 128; ++jt) {
    int j0 = jt * 32;
    __syncthreads();  // S1: prior iteration's PV reads (pp, gs) done
#pragma unroll
    for (int r = 0; r < 16; ++r) {  // stage phi rows j0..j0+31
      int idx = r * 256 + tid; int row = idx >> 7, k = idx & 127;
      pp[row][k] = phb[(size_t)(j0 + row) * NCI + k];
    }
#pragma unroll
    for (int r = 0; r < 16; ++r) {  // stage g half 0 (cc 0..127)
      int idx = r * 256 + tid; int cc = idx >> 5, jj = idx & 31;
      gs[cc][jj] = gb[(size_t)cc * NPOS + j0 + jj];
    }
    __syncthreads();  // S2
    float4 sa0 = {0, 0, 0, 0}, sa1 = {0, 0, 0, 0}, sa2 = {0, 0, 0, 0}, sa3 = {0, 0, 0, 0};
#pragma unroll
    for (int k4 = 0; k4 < 32; ++k4) {
      float4 ta = *(const float4*)&th[ty][k4 * 4];
      float4 tb = *(const float4*)&th[ty + 16][k4 * 4];
      float4 pa = *(const float4*)&pp[tx][k4 * 4];
      float4 pb = *(const float4*)&pp[tx + 16][k4 * 4];
      DOT_ACC(sa0, ta, pa); DOT_ACC(sa1, ta, pb);
      DOT_ACC(sa2, tb, pa); DOT_ACC(sa3, tb, pb);
    }
    float s00 = sa0.x + sa0.y + sa0.z + sa0.w;
    float s01 = sa1.x + sa1.y + sa1.z + sa1.w;
    float s10 = sa2.x + sa2.y + sa2.z + sa2.w;
    float s11 = sa3.x + sa3.y + sa3.z + sa3.w;
    float mja = mb[j0 + tx], mjb = mb[j0 + tx + 16];
    float lva = lvb[j0 + tx], lvbv = lvb[j0 + tx + 16];
    float p00 = __expf(s00 - mja) * lva;
    float p01 = __expf(s01 - mjb) * lvbv;
    float p10 = __expf(s10 - mja) * lva;
    float p11 = __expf(s11 - mjb) * lvbv;
    __syncthreads();  // S3: all dot reads of pp done before overwrite with P
    pp[ty][tx] = p00; pp[ty][tx + 16] = p01;
    pp[ty + 16][tx] = p10; pp[ty + 16][tx + 16] = p11;
    __syncthreads();  // S4
#pragma unroll
    for (int h2 = 0; h2 < 2; ++h2) {
      if (h2 == 1) {
        __syncthreads();  // S5: half-0 PV reads of gs done
#pragma unroll
        for (int r = 0; r < 16; ++r) {
          int idx = r * 256 + tid; int cc = idx >> 5, jj = idx & 31;
          gs[cc][jj] = gb[(size_t)(128 + cc) * NPOS + j0 + jj];
        }
        __syncthreads();  // S6
      }
#pragma unroll
      for (int j4 = 0; j4 < 8; ++j4) {
        float4 pa = *(const float4*)&pp[ty][j4 * 4];
        float4 pb = *(const float4*)&pp[ty + 16][j4 * 4];
#pragma unroll
        for (int hh = 0; hh < 8; ++hh) {
          float4 gv = *(const float4*)&gs[tx + hh * 16][j4 * 4];
          acc[0][h2 * 8 + hh] += pa.x * gv.x + pa.y * gv.y + pa.z * gv.z + pa.w * gv.w;
          acc[1][h2 * 8 + hh] += pb.x * gv.x + pb.y * gv.y + pb.z * gv.z + pb.w * gv.w;
        }
      }
    }
  }
  // write omid channel-major
#pragma unroll
  for (int hh = 0; hh < 16; ++hh) {
    int cc = (hh < 8) ? (tx + hh * 16) : (128 + tx + (hh - 8) * 16);
    size_t base = (size_t)b * NC * NPOS + (size_t)cc * NPOS + i0;
    omid[base + ty] = acc[0][hh];
    omid[base + ty + 16] = acc[1][hh];
  }
}

extern "C" void kernel_launch(void* const* d_in, const int* in_sizes, int n_in,
                              void* d_out, int out_size, void* d_ws, size_t ws_size,
                              hipStream_t stream) {
  (void)in_sizes; (void)n_in; (void)out_size; (void)ws_size;
  const float* x0     = (const float*)d_in[0];
  const float* x      = (const float*)d_in[1];
  const float* x_dsm  = (const float*)d_in[2];
  const float* w_phi  = (const float*)d_in[3];
  const float* w_theta= (const float*)d_in[4];
  const float* w_g    = (const float*)d_in[5];
  const float* w_mask = (const float*)d_in[6];
  float* outp = (float*)d_out;

  float* w = (float*)d_ws;
  float* wt_phi   = w; w += (size_t)NC * NCI;     // [256][128]
  float* wt_theta = w; w += (size_t)NC * NCI;     // [256][128]
  float* wt_g     = w; w += (size_t)NC2 * NC;     // [512][256]
  float* wt_mask  = w; w += (size_t)NC * NC2;     // [256][512]
  float* phi      = w; w += (size_t)NB * NPOS * NCI;  // [b][p][128]
  float* theta    = w; w += (size_t)NB * NPOS * NCI;
  float* gbuf     = w; w += (size_t)NB * NC * NPOS;   // [b][cc][p]
  float* mbuf     = w; w += (size_t)NB * NPOS;
  float* linv     = w; w += (size_t)NB * NPOS;
  float* pm       = w; w += (size_t)NB * 2 * NPOS;
  float* pl       = w; w += (size_t)NB * 2 * NPOS;
  float* omid     = w; w += (size_t)NB * NC * NPOS;   // [b][cc][p]

  // transpose weights to [Cin][Cout]
  k_transpose<<<dim3(128), 256, 0, stream>>>(w_phi, wt_phi, NCI, NC);
  k_transpose<<<dim3(128), 256, 0, stream>>>(w_theta, wt_theta, NCI, NC);
  k_transpose<<<dim3(512), 256, 0, stream>>>(w_g, wt_g, NC, NC2);
  k_transpose<<<dim3(512), 256, 0, stream>>>(w_mask, wt_mask, NC2, NC);

  // 1x1 convs
  k_conv1x1<true, false><<<dim3(NPOS / 64, 1, NB), 256, 0, stream>>>(
      x, wt_phi, phi, nullptr, NC, NCI);
  k_conv1x1<true, false><<<dim3(NPOS / 64, 1, NB), 256, 0, stream>>>(
      x_dsm, wt_theta, theta, nullptr, NC, NCI);
  k_conv1x1<false, false><<<dim3(NPOS / 64, 2, NB), 256, 0, stream>>>(
      x0, wt_g, gbuf, nullptr, NC2, NC);

  // column softmax stats
  k_stats<<<dim3(NPOS / 32, 2, NB), 256, 0, stream>>>(phi, theta, pm, pl);
  k_combine<<<dim3(NB * NPOS / 256), 256, 0, stream>>>(pm, pl, mbuf, linv);

  // attention output
  k_out<<<dim3(NPOS / 32, NB), 256, 0, stream>>>(phi, theta, gbuf, mbuf, linv, omid);

  // mask conv + residual -> d_out
  k_conv1x1<false, true><<<dim3(NPOS / 64, 4, NB), 256, 0, stream>>>(
      omid, wt_mask, outp, x0, NC, NC2);
}

// Round 4
// 385.407 us; speedup vs baseline: 12.9604x; 12.9604x over previous
//
#include <hip/hip_runtime.h>
#include <math.h>

#define NB 4
#define NC 256
#define NCI 128
#define NC2 512
#define NPOS 4096

using bf16x8 = __attribute__((ext_vector_type(8))) short;
using f32x4  = __attribute__((ext_vector_type(4))) float;

__device__ inline unsigned short f2bf(float f) {
  unsigned int u = __float_as_uint(f);
  u = (u + 0x7fffu + ((u >> 16) & 1u)) >> 16;
  return (unsigned short)u;
}
__device__ inline float bf2f(short s) {
  return __uint_as_float(((unsigned int)(unsigned short)s) << 16);
}

// ---------------- transpose weights: dst[c][o] = src[o][c] ----------------
__global__ void k_transpose(const float* __restrict__ src, float* __restrict__ dst,
                            int rows, int cols) {
  int i = blockIdx.x * 256 + threadIdx.x;
  if (i < rows * cols) {
    int o = i / cols, c = i % cols;
    dst[c * rows + o] = src[i];
  }
}

// ---------------- fp32 1x1 conv, channel-major out + residual (mask conv) --------
__global__ __launch_bounds__(256) void k_conv_mask(
    const float* __restrict__ in, const float* __restrict__ wt,
    float* __restrict__ out, const float* __restrict__ res,
    int Cin, int Cout) {
  __shared__ float xs[32][68];
  __shared__ float wsh[32][132];
  const int tid = threadIdx.x;
  const int tp = tid & 15, to = tid >> 4;
  const int p0 = blockIdx.x * 64, o0 = blockIdx.y * 128, b = blockIdx.z;
  const float* inb = in + (size_t)b * Cin * NPOS + p0;
  float acc[8][4] = {};
  for (int c0 = 0; c0 < Cin; c0 += 32) {
    __syncthreads();
#pragma unroll
    for (int r = 0; r < 8; ++r) {
      int idx = r * 256 + tid; int k = idx >> 6, p = idx & 63;
      xs[k][p] = inb[(size_t)(c0 + k) * NPOS + p];
    }
#pragma unroll
    for (int r = 0; r < 16; ++r) {
      int idx = r * 256 + tid; int k = idx >> 7, o = idx & 127;
      wsh[k][o] = wt[(size_t)(c0 + k) * Cout + o0 + o];
    }
    __syncthreads();
#pragma unroll
    for (int k = 0; k < 32; ++k) {
      float4 xv = *(const float4*)&xs[k][tp * 4];
      float4 w0 = *(const float4*)&wsh[k][to * 8];
      float4 w1 = *(const float4*)&wsh[k][to * 8 + 4];
      float wv[8] = {w0.x, w0.y, w0.z, w0.w, w1.x, w1.y, w1.z, w1.w};
      float xa[4] = {xv.x, xv.y, xv.z, xv.w};
#pragma unroll
      for (int r = 0; r < 8; ++r)
#pragma unroll
        for (int c = 0; c < 4; ++c)
          acc[r][c] += wv[r] * xa[c];
    }
  }
#pragma unroll
  for (int r = 0; r < 8; ++r) {
    int o = o0 + to * 8 + r;
    size_t oi = (size_t)b * Cout * NPOS + (size_t)o * NPOS + p0 + tp * 4;
    float4 rv = *(const float4*)&res[oi];
    float4 v = {acc[r][0] + rv.x, acc[r][1] + rv.y, acc[r][2] + rv.z, acc[r][3] + rv.w};
    *(float4*)&out[oi] = v;
  }
}

// ---------------- 1x1 conv -> bf16 pos-major [p][128] (phi/theta) ----------------
__global__ __launch_bounds__(256) void k_conv_pm_bf16(
    const float* __restrict__ in, const float* __restrict__ wt,
    short* __restrict__ out) {
  __shared__ float xs[32][68];
  __shared__ float wsh[32][132];
  const int tid = threadIdx.x;
  const int tp = tid & 15, to = tid >> 4;
  const int p0 = blockIdx.x * 64, b = blockIdx.z;
  const float* inb = in + (size_t)b * NC * NPOS + p0;
  float acc[8][4] = {};
  for (int c0 = 0; c0 < NC; c0 += 32) {
    __syncthreads();
#pragma unroll
    for (int r = 0; r < 8; ++r) {
      int idx = r * 256 + tid; int k = idx >> 6, p = idx & 63;
      xs[k][p] = inb[(size_t)(c0 + k) * NPOS + p];
    }
#pragma unroll
    for (int r = 0; r < 16; ++r) {
      int idx = r * 256 + tid; int k = idx >> 7, o = idx & 127;
      wsh[k][o] = wt[(size_t)(c0 + k) * NCI + o];
    }
    __syncthreads();
#pragma unroll
    for (int k = 0; k < 32; ++k) {
      float4 xv = *(const float4*)&xs[k][tp * 4];
      float4 w0 = *(const float4*)&wsh[k][to * 8];
      float4 w1 = *(const float4*)&wsh[k][to * 8 + 4];
      float wv[8] = {w0.x, w0.y, w0.z, w0.w, w1.x, w1.y, w1.z, w1.w};
      float xa[4] = {xv.x, xv.y, xv.z, xv.w};
#pragma unroll
      for (int r = 0; r < 8; ++r)
#pragma unroll
        for (int c = 0; c < 4; ++c)
          acc[r][c] += wv[r] * xa[c];
    }
  }
  short* ob = out + (size_t)b * NPOS * NCI;
#pragma unroll
  for (int c = 0; c < 4; ++c) {
    int p = p0 + tp * 4 + c;
    short v[8];
#pragma unroll
    for (int r = 0; r < 8; ++r) v[r] = (short)f2bf(acc[r][c]);
    *(int4*)(ob + (size_t)p * NCI + to * 8) = *(const int4*)v;
  }
}

// ---------------- 1x1 conv -> bf16 channel-major [cc][p] (g) ----------------
__global__ __launch_bounds__(256) void k_conv_cm_bf16(
    const float* __restrict__ in, const float* __restrict__ wt,
    short* __restrict__ out) {
  __shared__ float xs[32][68];
  __shared__ float wsh[32][132];
  const int tid = threadIdx.x;
  const int tp = tid & 15, to = tid >> 4;
  const int p0 = blockIdx.x * 64, o0 = blockIdx.y * 128, b = blockIdx.z;
  const float* inb = in + (size_t)b * NC2 * NPOS + p0;
  float acc[8][4] = {};
  for (int c0 = 0; c0 < NC2; c0 += 32) {
    __syncthreads();
#pragma unroll
    for (int r = 0; r < 8; ++r) {
      int idx = r * 256 + tid; int k = idx >> 6, p = idx & 63;
      xs[k][p] = inb[(size_t)(c0 + k) * NPOS + p];
    }
#pragma unroll
    for (int r = 0; r < 16; ++r) {
      int idx = r * 256 + tid; int k = idx >> 7, o = idx & 127;
      wsh[k][o] = wt[(size_t)(c0 + k) * NC + o0 + o];
    }
    __syncthreads();
#pragma unroll
    for (int k = 0; k < 32; ++k) {
      float4 xv = *(const float4*)&xs[k][tp * 4];
      float4 w0 = *(const float4*)&wsh[k][to * 8];
      float4 w1 = *(const float4*)&wsh[k][to * 8 + 4];
      float wv[8] = {w0.x, w0.y, w0.z, w0.w, w1.x, w1.y, w1.z, w1.w};
      float xa[4] = {xv.x, xv.y, xv.z, xv.w};
#pragma unroll
      for (int r = 0; r < 8; ++r)
#pragma unroll
        for (int c = 0; c < 4; ++c)
          acc[r][c] += wv[r] * xa[c];
    }
  }
  short* ob = out + (size_t)b * NC * NPOS;
#pragma unroll
  for (int r = 0; r < 8; ++r) {
    int o = o0 + to * 8 + r;
    short v[4];
#pragma unroll
    for (int c = 0; c < 4; ++c) v[c] = (short)f2bf(acc[r][c]);
    *(uint2*)(ob + (size_t)o * NPOS + p0 + tp * 4) = *(const uint2*)v;
  }
}

// ---------------- l[j] = sum_i exp(s[i][j]); writes linv = 1/l ----------------
// S^T[j][i] = phi_row[j] . theta_row[i], MFMA: A=phi, B=theta.
__global__ __launch_bounds__(256, 1) void k_lsum(
    const short* __restrict__ phiB, const short* __restrict__ thetaB,
    float* __restrict__ linv) {
  __shared__ short thT[2][64 * 128];   // 16KB each, chunk-swizzled
  const int tid = threadIdx.x, lane = tid & 63, w = tid >> 6;
  const int x = lane & 15, q = lane >> 4;
  const int j0 = blockIdx.x * 64, b = blockIdx.y;
  const short* phb = phiB + (size_t)b * NPOS * NCI;
  const short* thb = thetaB + (size_t)b * NPOS * NCI;
  // A-frags (phi rows j0 + w*16 + x), k chunk = q + 4*kk, from global once
  bf16x8 af[4];
  {
    const short* pr = phb + (size_t)(j0 + w * 16 + x) * NCI;
#pragma unroll
    for (int kk = 0; kk < 4; ++kk) af[kk] = *(const bf16x8*)(pr + kk * 32 + q * 8);
  }
  float lsum[4] = {0.f, 0.f, 0.f, 0.f};
  int4 rt[4];
  const int NIT = NPOS / 64;
#define LSUM_LOAD(it)                                                         \
  {                                                                           \
    _Pragma("unroll") for (int r = 0; r < 4; ++r) {                           \
      int s = tid + r * 256; int row = s >> 4, c = s & 15;                    \
      rt[r] = *(const int4*)(thb + (size_t)((it) * 64 + row) * NCI + c * 8);  \
    }                                                                         \
  }
#define LSUM_WRITE(buf)                                                       \
  {                                                                           \
    _Pragma("unroll") for (int r = 0; r < 4; ++r) {                           \
      int s = tid + r * 256; int row = s >> 4, c = s & 15;                    \
      *(int4*)(&thT[buf][row * 128 + ((c ^ (row & 7)) * 8)]) = rt[r];         \
    }                                                                         \
  }
  LSUM_LOAD(0); LSUM_WRITE(0); __syncthreads();
  int cur = 0;
  for (int it = 0; it < NIT; ++it) {
    if (it + 1 < NIT) LSUM_LOAD(it + 1);
#pragma unroll
    for (int ii = 0; ii < 4; ++ii) {
      f32x4 s = {0.f, 0.f, 0.f, 0.f};
      int row = ii * 16 + x;
      int sw = row & 7;
#pragma unroll
      for (int kk = 0; kk < 4; ++kk) {
        bf16x8 bf = *(const bf16x8*)(&thT[cur][row * 128 + (((kk * 4 + q) ^ sw) * 8)]);
        s = __builtin_amdgcn_mfma_f32_16x16x32_bf16(af[kk], bf, s, 0, 0, 0);
      }
#pragma unroll
      for (int r = 0; r < 4; ++r) lsum[r] += __expf(s[r]);
    }
    if (it + 1 < NIT) LSUM_WRITE(cur ^ 1);
    __syncthreads();
    cur ^= 1;
  }
#pragma unroll
  for (int m = 1; m < 16; m <<= 1)
#pragma unroll
    for (int r = 0; r < 4; ++r) lsum[r] += __shfl_xor(lsum[r], m);
  if (x == 0) {
#pragma unroll
    for (int r = 0; r < 4; ++r)
      linv[(size_t)b * NPOS + j0 + w * 16 + 4 * q + r] = 1.0f / lsum[r];
  }
}

// ---------------- fold linv into g: gB[cc][p] *= linv[p] ----------------
__global__ void k_scale_g(short* __restrict__ gB, const float* __restrict__ linv) {
  size_t e = ((size_t)blockIdx.x * 256 + threadIdx.x) * 8;
  int b = (int)(e >> 20);          // 256*4096 = 2^20
  int p = (int)(e & (NPOS - 1));
  short v[8];
  *(int4*)v = *(const int4*)(gB + e);
  const float* lv = linv + ((size_t)b << 12) + p;
#pragma unroll
  for (int k = 0; k < 8; ++k) v[k] = (short)f2bf(bf2f(v[k]) * lv[k]);
  *(int4*)(gB + e) = *(const int4*)v;
}

// ---------------- attention output: omid[cc][i] = sum_j exp(s[i][j]) * g'[cc][j] ----
// Per block: 64 i rows (4 waves x 16), loop j in tiles of 32.
// S^T = mfma(A=phi, B=theta-in-regs); P -> per-wave LDS tile; PV = mfma(A=P, B=g).
__global__ __launch_bounds__(256, 1) void k_attn(
    const short* __restrict__ phiB, const short* __restrict__ thetaB,
    const short* __restrict__ gB, float* __restrict__ omid) {
  __shared__ short phiT[2][32 * 128];   // 8KB each, chunk-swizzled (^ row&7)
  __shared__ short gT[2][256 * 32];     // 16KB each, linear
  __shared__ short pT[4][16 * 32];      // 1KB per wave, chunk-swizzled (^ (x>>1)&3)
  const int tid = threadIdx.x, lane = tid & 63, w = tid >> 6;
  const int x = lane & 15, q = lane >> 4;
  const int i0 = blockIdx.x * 64, b = blockIdx.y;
  const short* phb = phiB + (size_t)b * NPOS * NCI;
  const short* thb = thetaB + (size_t)b * NPOS * NCI;
  const short* gb = gB + (size_t)b * NC * NPOS;

  // theta B-frags in regs: col i = i0 + w*16 + x, k chunk q + 4*kk
  bf16x8 tf[4];
  {
    const short* tr = thb + (size_t)(i0 + w * 16 + x) * NCI;
#pragma unroll
    for (int kk = 0; kk < 4; ++kk) tf[kk] = *(const bf16x8*)(tr + kk * 32 + q * 8);
  }
  f32x4 acc[16];
#pragma unroll
  for (int i = 0; i < 16; ++i) acc[i] = (f32x4){0.f, 0.f, 0.f, 0.f};

  int4 rphi[2], rg[4];
  const int NT = NPOS / 32;   // 128
#define ATTN_LOAD(jt)                                                          \
  {                                                                            \
    _Pragma("unroll") for (int r = 0; r < 2; ++r) {                            \
      int s = tid + r * 256; int row = s >> 4, c = s & 15;                     \
      rphi[r] = *(const int4*)(phb + (size_t)((jt) * 32 + row) * NCI + c * 8); \
    }                                                                          \
    _Pragma("unroll") for (int r = 0; r < 4; ++r) {                            \
      int s = tid + r * 256; int cc = s >> 2, c4 = s & 3;                      \
      rg[r] = *(const int4*)(gb + (size_t)cc * NPOS + (jt) * 32 + c4 * 8);     \
    }                                                                          \
  }
#define ATTN_WRITE(buf)                                                        \
  {                                                                            \
    _Pragma("unroll") for (int r = 0; r < 2; ++r) {                            \
      int s = tid + r * 256; int row = s >> 4, c = s & 15;                     \
      *(int4*)(&phiT[buf][row * 128 + ((c ^ (row & 7)) * 8)]) = rphi[r];       \
    }                                                                          \
    _Pragma("unroll") for (int r = 0; r < 4; ++r) {                            \
      int s = tid + r * 256; int cc = s >> 2, c4 = s & 3;                      \
      *(int4*)(&gT[buf][cc * 32 + c4 * 8]) = rg[r];                            \
    }                                                                          \
  }
  ATTN_LOAD(0); ATTN_WRITE(0); __syncthreads();
  int cur = 0;
  for (int jt = 0; jt < NT; ++jt) {
    if (jt + 1 < NT) ATTN_LOAD(jt + 1);
    {
      const short* PH = &phiT[cur][0];
      const short* GT = &gT[cur][0];
      short* PW = &pT[w][0];
      // S^T, two 16-j sub-tiles
#pragma unroll
      for (int jsub = 0; jsub < 2; ++jsub) {
        f32x4 s = {0.f, 0.f, 0.f, 0.f};
        int row = jsub * 16 + x;
        int sw = row & 7;
#pragma unroll
        for (int kk = 0; kk < 4; ++kk) {
          bf16x8 a = *(const bf16x8*)(PH + row * 128 + (((kk * 4 + q) ^ sw) * 8));
          s = __builtin_amdgcn_mfma_f32_16x16x32_bf16(a, tf[kk], s, 0, 0, 0);
        }
        // lane holds S^T[j = 4q+r][i = x]; P = exp(S)
        unsigned short p0 = f2bf(__expf(s[0]));
        unsigned short p1 = f2bf(__expf(s[1]));
        unsigned short p2 = f2bf(__expf(s[2]));
        unsigned short p3 = f2bf(__expf(s[3]));
        unsigned int lo = (unsigned int)p0 | ((unsigned int)p1 << 16);
        unsigned int hi = (unsigned int)p2 | ((unsigned int)p3 << 16);
        int byteoff = (x * 64 + jsub * 32 + q * 8) ^ (((x >> 1) & 3) << 4);
        *(uint2*)((char*)PW + byteoff) = make_uint2(lo, hi);
      }
      // PV: A = P[i=x][jj=8q..8q+7], B = g'[jj][cc]
      {
        int c = q ^ ((x >> 1) & 3);
        bf16x8 ap = *(const bf16x8*)((const char*)PW + x * 64 + c * 16);
#pragma unroll
        for (int cf = 0; cf < 16; ++cf) {
          bf16x8 bg = *(const bf16x8*)(GT + (cf * 16 + x) * 32 + q * 8);
          acc[cf] = __builtin_amdgcn_mfma_f32_16x16x32_bf16(ap, bg, acc[cf], 0, 0, 0);
        }
      }
    }
    if (jt + 1 < NT) ATTN_WRITE(cur ^ 1);
    __syncthreads();
    cur ^= 1;
  }
  // store: D[iloc=4q+r][ccloc=x]; omid channel-major [cc][i]
#pragma unroll
  for (int cf = 0; cf < 16; ++cf) {
    size_t o = ((size_t)b * NC + cf * 16 + x) * NPOS + i0 + w * 16 + 4 * q;
    *reinterpret_cast<f32x4*>(&omid[o]) = acc[cf];
  }
}

extern "C" void kernel_launch(void* const* d_in, const int* in_sizes, int n_in,
                              void* d_out, int out_size, void* d_ws, size_t ws_size,
                              hipStream_t stream) {
  (void)in_sizes; (void)n_in; (void)out_size; (void)ws_size;
  const float* x0      = (const float*)d_in[0];
  const float* x       = (const float*)d_in[1];
  const float* x_dsm   = (const float*)d_in[2];
  const float* w_phi   = (const float*)d_in[3];
  const float* w_theta = (const float*)d_in[4];
  const float* w_g     = (const float*)d_in[5];
  const float* w_mask  = (const float*)d_in[6];
  float* outp = (float*)d_out;

  float* w = (float*)d_ws;
  float* wt_phi   = w; w += (size_t)NC * NCI;
  float* wt_theta = w; w += (size_t)NC * NCI;
  float* wt_g     = w; w += (size_t)NC2 * NC;
  float* wt_mask  = w; w += (size_t)NC * NC2;
  short* s = (short*)w;
  short* phiB   = s; s += (size_t)NB * NPOS * NCI;
  short* thetaB = s; s += (size_t)NB * NPOS * NCI;
  short* gBuf   = s; s += (size_t)NB * NC * NPOS;
  float* w2 = (float*)s;
  float* linv = w2; w2 += (size_t)NB * NPOS;
  float* omid = w2; w2 += (size_t)NB * NC * NPOS;

  k_transpose<<<dim3(128), 256, 0, stream>>>(w_phi, wt_phi, NCI, NC);
  k_transpose<<<dim3(128), 256, 0, stream>>>(w_theta, wt_theta, NCI, NC);
  k_transpose<<<dim3(512), 256, 0, stream>>>(w_g, wt_g, NC, NC2);
  k_transpose<<<dim3(512), 256, 0, stream>>>(w_mask, wt_mask, NC2, NC);

  k_conv_pm_bf16<<<dim3(NPOS / 64, 1, NB), 256, 0, stream>>>(x, wt_phi, phiB);
  k_conv_pm_bf16<<<dim3(NPOS / 64, 1, NB), 256, 0, stream>>>(x_dsm, wt_theta, thetaB);
  k_conv_cm_bf16<<<dim3(NPOS / 64, 2, NB), 256, 0, stream>>>(x0, wt_g, gBuf);

  k_lsum<<<dim3(NPOS / 64, NB), 256, 0, stream>>>(phiB, thetaB, linv);
  k_scale_g<<<dim3((NB * NC * NPOS / 8) / 256), 256, 0, stream>>>(gBuf, linv);

  k_attn<<<dim3(NPOS / 64, NB), 256, 0, stream>>>(phiB, thetaB, gBuf, omid);

  k_conv_mask<<<dim3(NPOS / 64, 4, NB), 256, 0, stream>>>(
      omid, wt_mask, outp, x0, NC, NC2);
}

// Round 5
// 335.369 us; speedup vs baseline: 14.8941x; 1.1492x over previous
//
#include <hip/hip_runtime.h>
#include <math.h>

#define NB 4
#define NC 256
#define NCI 128
#define NC2 512
#define NPOS 4096

using bf16x8 = __attribute__((ext_vector_type(8))) short;
using f32x4  = __attribute__((ext_vector_type(4))) float;

__device__ inline unsigned short f2bf(float f) {
  unsigned int u = __float_as_uint(f);
  u = (u + 0x7fffu + ((u >> 16) & 1u)) >> 16;
  return (unsigned short)u;
}
__device__ inline float bf2f(short s) {
  return __uint_as_float(((unsigned int)(unsigned short)s) << 16);
}

// ---------------- cast 4 weight tensors fp32 -> bf16 ----------------
__global__ void k_cast4(const float* __restrict__ s0, short* __restrict__ d0, int n0,
                        const float* __restrict__ s1, short* __restrict__ d1, int n1,
                        const float* __restrict__ s2, short* __restrict__ d2, int n2,
                        const float* __restrict__ s3, short* __restrict__ d3, int n3) {
  int i = blockIdx.x * 256 + threadIdx.x;
  if (i < n0) { d0[i] = (short)f2bf(s0[i]); return; } i -= n0;
  if (i < n1) { d1[i] = (short)f2bf(s1[i]); return; } i -= n1;
  if (i < n2) { d2[i] = (short)f2bf(s2[i]); return; } i -= n2;
  if (i < n3) { d3[i] = (short)f2bf(s3[i]); }
}

// ---------------- transpose-cast: in [b][R][C] f32 -> out [b][C][R] bf16 -------
__global__ __launch_bounds__(256) void k_tcast(
    const float* __restrict__ in, short* __restrict__ out,
    int R, int C, size_t inBs, size_t outBs) {
  __shared__ float t[64][65];
  const int tid = threadIdx.x;
  const int r0 = blockIdx.y * 64, c0 = blockIdx.x * 64, b = blockIdx.z;
  {
    int r = tid >> 2, cc = (tid & 3) * 16;
    const float* ib = in + (size_t)b * inBs + (size_t)(r0 + r) * C + c0 + cc;
#pragma unroll
    for (int i = 0; i < 4; ++i) {
      float4 v = *(const float4*)(ib + i * 4);
      t[r][cc + i * 4 + 0] = v.x; t[r][cc + i * 4 + 1] = v.y;
      t[r][cc + i * 4 + 2] = v.z; t[r][cc + i * 4 + 3] = v.w;
    }
  }
  __syncthreads();
  {
    int c = tid >> 2, rr = (tid & 3) * 16;
    __align__(16) short v[16];
#pragma unroll
    for (int i = 0; i < 16; ++i) v[i] = (short)f2bf(t[rr + i][c]);
    short* ob = out + (size_t)b * outBs + (size_t)(c0 + c) * R + r0 + rr;
    *(int4*)(ob) = *(const int4*)(v);
    *(int4*)(ob + 8) = *(const int4*)(v + 8);
  }
}

// same, summing two f32 sources (combines the two j-half partials of omid)
__global__ __launch_bounds__(256) void k_tcast2(
    const float* __restrict__ inA, const float* __restrict__ inB,
    short* __restrict__ out, int R, int C, size_t inBs, size_t outBs) {
  __shared__ float t[64][65];
  const int tid = threadIdx.x;
  const int r0 = blockIdx.y * 64, c0 = blockIdx.x * 64, b = blockIdx.z;
  {
    int r = tid >> 2, cc = (tid & 3) * 16;
    size_t base = (size_t)b * inBs + (size_t)(r0 + r) * C + c0 + cc;
#pragma unroll
    for (int i = 0; i < 4; ++i) {
      float4 va = *(const float4*)(inA + base + i * 4);
      float4 vb = *(const float4*)(inB + base + i * 4);
      t[r][cc + i * 4 + 0] = va.x + vb.x; t[r][cc + i * 4 + 1] = va.y + vb.y;
      t[r][cc + i * 4 + 2] = va.z + vb.z; t[r][cc + i * 4 + 3] = va.w + vb.w;
    }
  }
  __syncthreads();
  {
    int c = tid >> 2, rr = (tid & 3) * 16;
    __align__(16) short v[16];
#pragma unroll
    for (int i = 0; i < 16; ++i) v[i] = (short)f2bf(t[rr + i][c]);
    short* ob = out + (size_t)b * outBs + (size_t)(c0 + c) * R + r0 + rr;
    *(int4*)(ob) = *(const int4*)(v);
    *(int4*)(ob + 8) = *(const int4*)(v + 8);
  }
}

// ---------------- generic bf16 MFMA GEMM ----------------
// C[m][n] = sum_k A[m][k]*B[n][k]; A:[M][K] bf16 (batch stride aBs),
// B:[N][K] bf16 (bBs). out elem addr = b*oBs + n*sN + m (m contiguous).
// OUT_BF16: bf16 store; else f32 (+res, same indexing as out).
template<bool OUT_BF16, bool HAS_RES>
__global__ __launch_bounds__(256) void k_gemm(
    const short* __restrict__ A, const short* __restrict__ B,
    void* __restrict__ outv, const float* __restrict__ res,
    int K, int sN, size_t aBs, size_t bBs, size_t oBs) {
  __shared__ short As[2][64 * 64];
  __shared__ short Bs_[2][64 * 64];
  const int tid = threadIdx.x, lane = tid & 63, w = tid >> 6;
  const int x = lane & 15, q = lane >> 4;
  const int wm = (w & 1) * 32, wn = (w >> 1) * 32;
  const int n0 = blockIdx.x * 64, m0 = blockIdx.y * 64, b = blockIdx.z;
  const short* Ab = A + (size_t)b * aBs + (size_t)m0 * K;
  const short* Bb = B + (size_t)b * bBs + (size_t)n0 * K;
  const int r = tid >> 2, cth = tid & 3;
  f32x4 acc[2][2];
  acc[0][0] = acc[0][1] = acc[1][0] = acc[1][1] = (f32x4){0.f, 0.f, 0.f, 0.f};
  int4 ra[2], rb[2];
  const int NK = K >> 6;
#define GLOAD(kt)                                                              \
  { _Pragma("unroll") for (int i = 0; i < 2; ++i) {                            \
      ra[i] = *(const int4*)(Ab + (size_t)r * K + (kt) * 64 + (cth + i * 4) * 8); \
      rb[i] = *(const int4*)(Bb + (size_t)r * K + (kt) * 64 + (cth + i * 4) * 8); } }
#define GWRITE(buf)                                                            \
  { _Pragma("unroll") for (int i = 0; i < 2; ++i) {                            \
      *(int4*)(&As[buf][r * 64 + (((cth + i * 4) ^ (r & 7)) * 8)]) = ra[i];    \
      *(int4*)(&Bs_[buf][r * 64 + (((cth + i * 4) ^ (r & 7)) * 8)]) = rb[i]; } }
  GLOAD(0); GWRITE(0); __syncthreads();
  int cur = 0;
  for (int kt = 0; kt < NK; ++kt) {
    if (kt + 1 < NK) GLOAD(kt + 1);
    bf16x8 af[2][2], bfr[2][2];
#pragma unroll
    for (int ms = 0; ms < 2; ++ms) {
      int rowm = wm + ms * 16 + x;
#pragma unroll
      for (int ks = 0; ks < 2; ++ks)
        af[ms][ks] = *(const bf16x8*)(&As[cur][rowm * 64 + (((ks * 4 + q) ^ (rowm & 7)) * 8)]);
    }
#pragma unroll
    for (int ns = 0; ns < 2; ++ns) {
      int rown = wn + ns * 16 + x;
#pragma unroll
      for (int ks = 0; ks < 2; ++ks)
        bfr[ns][ks] = *(const bf16x8*)(&Bs_[cur][rown * 64 + (((ks * 4 + q) ^ (rown & 7)) * 8)]);
    }
#pragma unroll
    for (int ms = 0; ms < 2; ++ms)
#pragma unroll
      for (int ns = 0; ns < 2; ++ns)
#pragma unroll
        for (int ks = 0; ks < 2; ++ks)
          acc[ms][ns] = __builtin_amdgcn_mfma_f32_16x16x32_bf16(
              af[ms][ks], bfr[ns][ks], acc[ms][ns], 0, 0, 0);
    if (kt + 1 < NK) GWRITE(cur ^ 1);
    __syncthreads();
    cur ^= 1;
  }
#pragma unroll
  for (int ms = 0; ms < 2; ++ms)
#pragma unroll
    for (int ns = 0; ns < 2; ++ns) {
      int n = n0 + wn + ns * 16 + x;
      int m = m0 + wm + ms * 16 + q * 4;
      size_t off = (size_t)b * oBs + (size_t)n * sN + m;
      if (OUT_BF16) {
        __align__(8) short pv[4];
#pragma unroll
        for (int j = 0; j < 4; ++j) pv[j] = (short)f2bf(acc[ms][ns][j]);
        *(uint2*)((short*)outv + off) = *(const uint2*)pv;
      } else {
        float4 v = {acc[ms][ns][0], acc[ms][ns][1], acc[ms][ns][2], acc[ms][ns][3]};
        if (HAS_RES) {
          float4 rv = *(const float4*)(res + off);
          v.x += rv.x; v.y += rv.y; v.z += rv.z; v.w += rv.w;
        }
        *(float4*)((float*)outv + off) = v;
      }
    }
#undef GLOAD
#undef GWRITE
}

// ---------------- l[j] = sum_i exp(s[i][j]); writes linv = 1/l ----------------
__global__ __launch_bounds__(256, 1) void k_lsum(
    const short* __restrict__ phiB, const short* __restrict__ thetaB,
    float* __restrict__ linv) {
  __shared__ short thT[2][64 * 128];
  const int tid = threadIdx.x, lane = tid & 63, w = tid >> 6;
  const int x = lane & 15, q = lane >> 4;
  const int j0 = blockIdx.x * 64, b = blockIdx.y;
  const short* phb = phiB + (size_t)b * NPOS * NCI;
  const short* thb = thetaB + (size_t)b * NPOS * NCI;
  bf16x8 af[4];
  {
    const short* pr = phb + (size_t)(j0 + w * 16 + x) * NCI;
#pragma unroll
    for (int kk = 0; kk < 4; ++kk) af[kk] = *(const bf16x8*)(pr + kk * 32 + q * 8);
  }
  float lsum[4] = {0.f, 0.f, 0.f, 0.f};
  int4 rt[4];
  const int NIT = NPOS / 64;
#define LSUM_LOAD(it)                                                         \
  { _Pragma("unroll") for (int r = 0; r < 4; ++r) {                           \
      int s = tid + r * 256; int row = s >> 4, c = s & 15;                    \
      rt[r] = *(const int4*)(thb + (size_t)((it) * 64 + row) * NCI + c * 8); } }
#define LSUM_WRITE(buf)                                                       \
  { _Pragma("unroll") for (int r = 0; r < 4; ++r) {                           \
      int s = tid + r * 256; int row = s >> 4, c = s & 15;                    \
      *(int4*)(&thT[buf][row * 128 + ((c ^ (row & 7)) * 8)]) = rt[r]; } }
  LSUM_LOAD(0); LSUM_WRITE(0); __syncthreads();
  int cur = 0;
  for (int it = 0; it < NIT; ++it) {
    if (it + 1 < NIT) LSUM_LOAD(it + 1);
#pragma unroll
    for (int ii = 0; ii < 4; ++ii) {
      f32x4 s = {0.f, 0.f, 0.f, 0.f};
      int row = ii * 16 + x;
      int sw = row & 7;
#pragma unroll
      for (int kk = 0; kk < 4; ++kk) {
        bf16x8 bfv = *(const bf16x8*)(&thT[cur][row * 128 + (((kk * 4 + q) ^ sw) * 8)]);
        s = __builtin_amdgcn_mfma_f32_16x16x32_bf16(af[kk], bfv, s, 0, 0, 0);
      }
#pragma unroll
      for (int r = 0; r < 4; ++r) lsum[r] += __expf(s[r]);
    }
    if (it + 1 < NIT) LSUM_WRITE(cur ^ 1);
    __syncthreads();
    cur ^= 1;
  }
#pragma unroll
  for (int m = 1; m < 16; m <<= 1)
#pragma unroll
    for (int r = 0; r < 4; ++r) lsum[r] += __shfl_xor(lsum[r], m);
  if (x == 0) {
#pragma unroll
    for (int r = 0; r < 4; ++r)
      linv[(size_t)b * NPOS + j0 + w * 16 + 4 * q + r] = 1.0f / lsum[r];
  }
#undef LSUM_LOAD
#undef LSUM_WRITE
}

// ---------------- fold linv into g: gB[cc][p] *= linv[p] ----------------
__global__ void k_scale_g(short* __restrict__ gB, const float* __restrict__ linv) {
  size_t e = ((size_t)blockIdx.x * 256 + threadIdx.x) * 8;
  int b = (int)(e >> 20);
  int p = (int)(e & (NPOS - 1));
  __align__(16) short v[8];
  *(int4*)v = *(const int4*)(gB + e);
  const float* lv = linv + ((size_t)b << 12) + p;
#pragma unroll
  for (int k = 0; k < 8; ++k) v[k] = (short)f2bf(bf2f(v[k]) * lv[k]);
  *(int4*)(gB + e) = *(const int4*)v;
}

// ---------------- attention: omidP[jh][b][cc][i] = sum_{j in half} P*g' -------
__global__ __launch_bounds__(256, 1) void k_attn(
    const short* __restrict__ phiB, const short* __restrict__ thetaB,
    const short* __restrict__ gB, float* __restrict__ omidP) {
  __shared__ short phiT[2][32 * 128];
  __shared__ short gT[2][256 * 32];
  __shared__ short pT[4][16 * 32];
  const int tid = threadIdx.x, lane = tid & 63, w = tid >> 6;
  const int x = lane & 15, q = lane >> 4;
  const int i0 = blockIdx.x * 64, jh = blockIdx.y, b = blockIdx.z;
  const short* phb = phiB + (size_t)b * NPOS * NCI;
  const short* thb = thetaB + (size_t)b * NPOS * NCI;
  const short* gb = gB + (size_t)b * NC * NPOS;
  float* om = omidP + ((size_t)(jh * NB + b)) * NC * NPOS;

  bf16x8 tf[4];
  {
    const short* tr = thb + (size_t)(i0 + w * 16 + x) * NCI;
#pragma unroll
    for (int kk = 0; kk < 4; ++kk) tf[kk] = *(const bf16x8*)(tr + kk * 32 + q * 8);
  }
  f32x4 acc[16];
#pragma unroll
  for (int i = 0; i < 16; ++i) acc[i] = (f32x4){0.f, 0.f, 0.f, 0.f};

  const int sgx = (x & 3) ^ ((x >> 2) & 1);   // gT read swizzle (row-dependent, = f(x))
  int4 rphi[2], rg[4];
  const int NT = 64;                           // 64 j-tiles of 32 per half
  const int jbase = jh * 64;
#define ATTN_LOAD(jt)                                                          \
  { _Pragma("unroll") for (int r = 0; r < 2; ++r) {                            \
      int s = tid + r * 256; int row = s >> 4, c = s & 15;                     \
      rphi[r] = *(const int4*)(phb + (size_t)((jbase + (jt)) * 32 + row) * NCI + c * 8); } \
    _Pragma("unroll") for (int r = 0; r < 4; ++r) {                            \
      int s = tid + r * 256; int cc = s >> 2, c4 = s & 3;                      \
      rg[r] = *(const int4*)(gb + (size_t)cc * NPOS + (jbase + (jt)) * 32 + c4 * 8); } }
#define ATTN_WRITE(buf)                                                        \
  { _Pragma("unroll") for (int r = 0; r < 2; ++r) {                            \
      int s = tid + r * 256; int row = s >> 4, c = s & 15;                     \
      *(int4*)(&phiT[buf][row * 128 + ((c ^ (row & 7)) * 8)]) = rphi[r]; }     \
    _Pragma("unroll") for (int r = 0; r < 4; ++r) {                            \
      int s = tid + r * 256; int cc = s >> 2, c4 = s & 3;                      \
      int sw = (cc & 3) ^ ((cc >> 2) & 1);                                     \
      *(int4*)(&gT[buf][cc * 32 + ((c4 ^ sw) * 8)]) = rg[r]; } }
  ATTN_LOAD(0); ATTN_WRITE(0); __syncthreads();
  int cur = 0;
  for (int jt = 0; jt < NT; ++jt) {
    if (jt + 1 < NT) ATTN_LOAD(jt + 1);
    {
      const short* PH = &phiT[cur][0];
      const short* GT = &gT[cur][0];
      short* PW = &pT[w][0];
#pragma unroll
      for (int jsub = 0; jsub < 2; ++jsub) {
        f32x4 s = {0.f, 0.f, 0.f, 0.f};
        int row = jsub * 16 + x;
        int sw = row & 7;
#pragma unroll
        for (int kk = 0; kk < 4; ++kk) {
          bf16x8 a = *(const bf16x8*)(PH + row * 128 + (((kk * 4 + q) ^ sw) * 8));
          s = __builtin_amdgcn_mfma_f32_16x16x32_bf16(a, tf[kk], s, 0, 0, 0);
        }
        unsigned short p0 = f2bf(__expf(s[0]));
        unsigned short p1 = f2bf(__expf(s[1]));
        unsigned short p2 = f2bf(__expf(s[2]));
        unsigned short p3 = f2bf(__expf(s[3]));
        unsigned int lo = (unsigned int)p0 | ((unsigned int)p1 << 16);
        unsigned int hi = (unsigned int)p2 | ((unsigned int)p3 << 16);
        int byteoff = (x * 64 + jsub * 32 + q * 8) ^ ((((x >> 1) & 3)) << 4);
        *(uint2*)((char*)PW + byteoff) = make_uint2(lo, hi);
      }
      {
        int c = q ^ ((x >> 1) & 3);
        bf16x8 ap = *(const bf16x8*)((const char*)PW + x * 64 + c * 16);
#pragma unroll
        for (int cf = 0; cf < 16; ++cf) {
          bf16x8 bg = *(const bf16x8*)(GT + (cf * 16 + x) * 32 + ((q ^ sgx) * 8));
          acc[cf] = __builtin_amdgcn_mfma_f32_16x16x32_bf16(ap, bg, acc[cf], 0, 0, 0);
        }
      }
    }
    if (jt + 1 < NT) ATTN_WRITE(cur ^ 1);
    __syncthreads();
    cur ^= 1;
  }
#pragma unroll
  for (int cf = 0; cf < 16; ++cf) {
    size_t o = (size_t)(cf * 16 + x) * NPOS + i0 + w * 16 + 4 * q;
    *reinterpret_cast<f32x4*>(&om[o]) = acc[cf];
  }
#undef ATTN_LOAD
#undef ATTN_WRITE
}

extern "C" void kernel_launch(void* const* d_in, const int* in_sizes, int n_in,
                              void* d_out, int out_size, void* d_ws, size_t ws_size,
                              hipStream_t stream) {
  (void)in_sizes; (void)n_in; (void)out_size; (void)ws_size;
  const float* x0      = (const float*)d_in[0];
  const float* x       = (const float*)d_in[1];
  const float* x_dsm   = (const float*)d_in[2];
  const float* w_phi   = (const float*)d_in[3];
  const float* w_theta = (const float*)d_in[4];
  const float* w_g     = (const float*)d_in[5];
  const float* w_mask  = (const float*)d_in[6];
  float* outp = (float*)d_out;

  short* sp = (short*)d_ws;
  short* wb_phi   = sp; sp += 32768;                       // [128][256]
  short* wb_theta = sp; sp += 32768;                       // [128][256]
  short* wb_g     = sp; sp += 131072;                      // [256][512]
  short* wb_mask  = sp; sp += 131072;                      // [512][256]
  short* xT   = sp; sp += (size_t)NB * NPOS * NC;          // [b][p][256]
  short* xdT  = sp; sp += (size_t)NB * NPOS * NC;          // [b][p][256]
  short* x0T  = sp; sp += (size_t)NB * NPOS * NC2;         // [b][p][512]
  short* phiB   = sp; sp += (size_t)NB * NPOS * NCI;       // [b][p][128]
  short* thetaB = sp; sp += (size_t)NB * NPOS * NCI;
  short* gBuf   = sp; sp += (size_t)NB * NC * NPOS;        // [b][cc][p]
  float* linv = (float*)sp;                                // [b][p]
  float* omidP = (float*)xT;        // 32MB, aliases dead xT/xdT/x0T: [jh][b][cc][i]
  short* omidT = phiB;              // 8MB,  aliases dead phiB/thetaB: [b][p][256]

  k_cast4<<<dim3(1280), 256, 0, stream>>>(w_phi, wb_phi, 32768,
                                          w_theta, wb_theta, 32768,
                                          w_g, wb_g, 131072,
                                          w_mask, wb_mask, 131072);

  k_tcast<<<dim3(64, 4, NB), 256, 0, stream>>>(x, xT, NC, NPOS,
      (size_t)NC * NPOS, (size_t)NPOS * NC);
  k_tcast<<<dim3(64, 4, NB), 256, 0, stream>>>(x_dsm, xdT, NC, NPOS,
      (size_t)NC * NPOS, (size_t)NPOS * NC);
  k_tcast<<<dim3(64, 8, NB), 256, 0, stream>>>(x0, x0T, NC2, NPOS,
      (size_t)NC2 * NPOS, (size_t)NPOS * NC2);

  // phi[p][o] = sum_c W_phi[o][c] xT[p][c]  (m=o, n=p)
  k_gemm<true, false><<<dim3(64, 2, NB), 256, 0, stream>>>(
      wb_phi, xT, phiB, nullptr, NC, NCI, 0, (size_t)NPOS * NC, (size_t)NPOS * NCI);
  k_gemm<true, false><<<dim3(64, 2, NB), 256, 0, stream>>>(
      wb_theta, xdT, thetaB, nullptr, NC, NCI, 0, (size_t)NPOS * NC, (size_t)NPOS * NCI);
  // g[cc][p] = sum_c x0T[p][c] W_g[cc][c]  (m=p, n=cc)
  k_gemm<true, false><<<dim3(4, 64, NB), 256, 0, stream>>>(
      x0T, wb_g, gBuf, nullptr, NC2, NPOS, (size_t)NPOS * NC2, 0, (size_t)NC * NPOS);

  k_lsum<<<dim3(64, NB), 256, 0, stream>>>(phiB, thetaB, linv);
  k_scale_g<<<dim3(2048), 256, 0, stream>>>(gBuf, linv);

  k_attn<<<dim3(64, 2, NB), 256, 0, stream>>>(phiB, thetaB, gBuf, omidP);

  k_tcast2<<<dim3(64, 4, NB), 256, 0, stream>>>(omidP, omidP + (size_t)NB * NC * NPOS,
      omidT, NC, NPOS, (size_t)NC * NPOS, (size_t)NPOS * NC);

  // out[o2][p] = sum_cc omidT[p][cc] W_mask[o2][cc] + x0[o2][p]  (m=p, n=o2)
  k_gemm<false, true><<<dim3(8, 64, NB), 256, 0, stream>>>(
      omidT, wb_mask, outp, x0, NC, NPOS, (size_t)NPOS * NC, 0, (size_t)NC2 * NPOS);
}

// Round 6
// 255.280 us; speedup vs baseline: 19.5668x; 1.3137x over previous
//
#include <hip/hip_runtime.h>
#include <math.h>

#define NB 4
#define NC 256
#define NCI 128
#define NC2 512
#define NPOS 4096
#define ISPLIT 8

using bf16x8 = __attribute__((ext_vector_type(8))) short;
using f32x4  = __attribute__((ext_vector_type(4))) float;

__device__ inline unsigned short f2bf(float f) {
  unsigned int u = __float_as_uint(f);
  u = (u + 0x7fffu + ((u >> 16) & 1u)) >> 16;
  return (unsigned short)u;
}
__device__ inline float bf2f(short s) {
  return __uint_as_float(((unsigned int)(unsigned short)s) << 16);
}

// ---------------- cast 4 weight tensors fp32 -> bf16 ----------------
__global__ void k_cast4(const float* __restrict__ s0, short* __restrict__ d0, int n0,
                        const float* __restrict__ s1, short* __restrict__ d1, int n1,
                        const float* __restrict__ s2, short* __restrict__ d2, int n2,
                        const float* __restrict__ s3, short* __restrict__ d3, int n3) {
  int i = blockIdx.x * 256 + threadIdx.x;
  if (i < n0) { d0[i] = (short)f2bf(s0[i]); return; } i -= n0;
  if (i < n1) { d1[i] = (short)f2bf(s1[i]); return; } i -= n1;
  if (i < n2) { d2[i] = (short)f2bf(s2[i]); return; } i -= n2;
  if (i < n3) { d3[i] = (short)f2bf(s3[i]); }
}

// ---------------- transpose-cast: in [b][R][C] f32 -> out [b][C][R] bf16 -------
__global__ __launch_bounds__(256) void k_tcast(
    const float* __restrict__ in, short* __restrict__ out,
    int R, int C, size_t inBs, size_t outBs) {
  __shared__ float t[64][65];
  const int tid = threadIdx.x;
  const int r0 = blockIdx.y * 64, c0 = blockIdx.x * 64, b = blockIdx.z;
  {
    int r = tid >> 2, cc = (tid & 3) * 16;
    const float* ib = in + (size_t)b * inBs + (size_t)(r0 + r) * C + c0 + cc;
#pragma unroll
    for (int i = 0; i < 4; ++i) {
      float4 v = *(const float4*)(ib + i * 4);
      t[r][cc + i * 4 + 0] = v.x; t[r][cc + i * 4 + 1] = v.y;
      t[r][cc + i * 4 + 2] = v.z; t[r][cc + i * 4 + 3] = v.w;
    }
  }
  __syncthreads();
  {
    int c = tid >> 2, rr = (tid & 3) * 16;
    __align__(16) short v[16];
#pragma unroll
    for (int i = 0; i < 16; ++i) v[i] = (short)f2bf(t[rr + i][c]);
    short* ob = out + (size_t)b * outBs + (size_t)(c0 + c) * R + r0 + rr;
    *(int4*)(ob) = *(const int4*)(v);
    *(int4*)(ob + 8) = *(const int4*)(v + 8);
  }
}

// same, summing two f32 sources (combines the two j-half partials of omid)
__global__ __launch_bounds__(256) void k_tcast2(
    const float* __restrict__ inA, const float* __restrict__ inB,
    short* __restrict__ out, int R, int C, size_t inBs, size_t outBs) {
  __shared__ float t[64][65];
  const int tid = threadIdx.x;
  const int r0 = blockIdx.y * 64, c0 = blockIdx.x * 64, b = blockIdx.z;
  {
    int r = tid >> 2, cc = (tid & 3) * 16;
    size_t base = (size_t)b * inBs + (size_t)(r0 + r) * C + c0 + cc;
#pragma unroll
    for (int i = 0; i < 4; ++i) {
      float4 va = *(const float4*)(inA + base + i * 4);
      float4 vb = *(const float4*)(inB + base + i * 4);
      t[r][cc + i * 4 + 0] = va.x + vb.x; t[r][cc + i * 4 + 1] = va.y + vb.y;
      t[r][cc + i * 4 + 2] = va.z + vb.z; t[r][cc + i * 4 + 3] = va.w + vb.w;
    }
  }
  __syncthreads();
  {
    int c = tid >> 2, rr = (tid & 3) * 16;
    __align__(16) short v[16];
#pragma unroll
    for (int i = 0; i < 16; ++i) v[i] = (short)f2bf(t[rr + i][c]);
    short* ob = out + (size_t)b * outBs + (size_t)(c0 + c) * R + r0 + rr;
    *(int4*)(ob) = *(const int4*)(v);
    *(int4*)(ob + 8) = *(const int4*)(v + 8);
  }
}

// ---------------- generic bf16 MFMA GEMM ----------------
template<bool OUT_BF16, bool HAS_RES>
__global__ __launch_bounds__(256, 2) void k_gemm(
    const short* __restrict__ A, const short* __restrict__ B,
    void* __restrict__ outv, const float* __restrict__ res,
    int K, int sN, size_t aBs, size_t bBs, size_t oBs) {
  __shared__ short As[2][64 * 64];
  __shared__ short Bs_[2][64 * 64];
  const int tid = threadIdx.x, lane = tid & 63, w = tid >> 6;
  const int x = lane & 15, q = lane >> 4;
  const int wm = (w & 1) * 32, wn = (w >> 1) * 32;
  const int n0 = blockIdx.x * 64, m0 = blockIdx.y * 64, b = blockIdx.z;
  const short* Ab = A + (size_t)b * aBs + (size_t)m0 * K;
  const short* Bb = B + (size_t)b * bBs + (size_t)n0 * K;
  const int r = tid >> 2, cth = tid & 3;
  f32x4 acc[2][2];
  acc[0][0] = acc[0][1] = acc[1][0] = acc[1][1] = (f32x4){0.f, 0.f, 0.f, 0.f};
  int4 ra[2], rb[2];
  const int NK = K >> 6;
#define GLOAD(kt)                                                              \
  { _Pragma("unroll") for (int i = 0; i < 2; ++i) {                            \
      ra[i] = *(const int4*)(Ab + (size_t)r * K + (kt) * 64 + (cth + i * 4) * 8); \
      rb[i] = *(const int4*)(Bb + (size_t)r * K + (kt) * 64 + (cth + i * 4) * 8); } }
#define GWRITE(buf)                                                            \
  { _Pragma("unroll") for (int i = 0; i < 2; ++i) {                            \
      *(int4*)(&As[buf][r * 64 + (((cth + i * 4) ^ (r & 7)) * 8)]) = ra[i];    \
      *(int4*)(&Bs_[buf][r * 64 + (((cth + i * 4) ^ (r & 7)) * 8)]) = rb[i]; } }
  GLOAD(0); GWRITE(0); __syncthreads();
  int cur = 0;
  for (int kt = 0; kt < NK; ++kt) {
    if (kt + 1 < NK) GLOAD(kt + 1);
    bf16x8 af[2][2], bfr[2][2];
#pragma unroll
    for (int ms = 0; ms < 2; ++ms) {
      int rowm = wm + ms * 16 + x;
#pragma unroll
      for (int ks = 0; ks < 2; ++ks)
        af[ms][ks] = *(const bf16x8*)(&As[cur][rowm * 64 + (((ks * 4 + q) ^ (rowm & 7)) * 8)]);
    }
#pragma unroll
    for (int ns = 0; ns < 2; ++ns) {
      int rown = wn + ns * 16 + x;
#pragma unroll
      for (int ks = 0; ks < 2; ++ks)
        bfr[ns][ks] = *(const bf16x8*)(&Bs_[cur][rown * 64 + (((ks * 4 + q) ^ (rown & 7)) * 8)]);
    }
#pragma unroll
    for (int ms = 0; ms < 2; ++ms)
#pragma unroll
      for (int ns = 0; ns < 2; ++ns)
#pragma unroll
        for (int ks = 0; ks < 2; ++ks)
          acc[ms][ns] = __builtin_amdgcn_mfma_f32_16x16x32_bf16(
              af[ms][ks], bfr[ns][ks], acc[ms][ns], 0, 0, 0);
    if (kt + 1 < NK) GWRITE(cur ^ 1);
    __syncthreads();
    cur ^= 1;
  }
#pragma unroll
  for (int ms = 0; ms < 2; ++ms)
#pragma unroll
    for (int ns = 0; ns < 2; ++ns) {
      int n = n0 + wn + ns * 16 + x;
      int m = m0 + wm + ms * 16 + q * 4;
      size_t off = (size_t)b * oBs + (size_t)n * sN + m;
      if (OUT_BF16) {
        __align__(8) short pv[4];
#pragma unroll
        for (int j = 0; j < 4; ++j) pv[j] = (short)f2bf(acc[ms][ns][j]);
        *(uint2*)((short*)outv + off) = *(const uint2*)pv;
      } else {
        float4 v = {acc[ms][ns][0], acc[ms][ns][1], acc[ms][ns][2], acc[ms][ns][3]};
        if (HAS_RES) {
          float4 rv = *(const float4*)(res + off);
          v.x += rv.x; v.y += rv.y; v.z += rv.z; v.w += rv.w;
        }
        *(float4*)((float*)outv + off) = v;
      }
    }
#undef GLOAD
#undef GWRITE
}

// ---------------- partial l[j]: plsum[b][iy][j] = sum_{i in chunk} exp(s[i][j]) ----
__global__ __launch_bounds__(256, 4) void k_lsum(
    const short* __restrict__ phiB, const short* __restrict__ thetaB,
    float* __restrict__ plsum) {
  __shared__ short thT[2][64 * 128];
  const int tid = threadIdx.x, lane = tid & 63, w = tid >> 6;
  const int x = lane & 15, q = lane >> 4;
  const int j0 = blockIdx.x * 64, iy = blockIdx.y, b = blockIdx.z;
  const short* phb = phiB + (size_t)b * NPOS * NCI;
  const short* thb = thetaB + (size_t)b * NPOS * NCI + (size_t)iy * (NPOS / ISPLIT) * NCI;
  bf16x8 af[4];
  {
    const short* pr = phb + (size_t)(j0 + w * 16 + x) * NCI;
#pragma unroll
    for (int kk = 0; kk < 4; ++kk) af[kk] = *(const bf16x8*)(pr + kk * 32 + q * 8);
  }
  float lsum[4] = {0.f, 0.f, 0.f, 0.f};
  int4 rt[4];
  const int NIT = NPOS / ISPLIT / 64;   // 8
#define LSUM_LOAD(it)                                                         \
  { _Pragma("unroll") for (int r = 0; r < 4; ++r) {                           \
      int s = tid + r * 256; int row = s >> 4, c = s & 15;                    \
      rt[r] = *(const int4*)(thb + (size_t)((it) * 64 + row) * NCI + c * 8); } }
#define LSUM_WRITE(buf)                                                       \
  { _Pragma("unroll") for (int r = 0; r < 4; ++r) {                           \
      int s = tid + r * 256; int row = s >> 4, c = s & 15;                    \
      *(int4*)(&thT[buf][row * 128 + ((c ^ (row & 7)) * 8)]) = rt[r]; } }
  LSUM_LOAD(0); LSUM_WRITE(0); __syncthreads();
  int cur = 0;
  for (int it = 0; it < NIT; ++it) {
    if (it + 1 < NIT) LSUM_LOAD(it + 1);
#pragma unroll
    for (int ii = 0; ii < 4; ++ii) {
      f32x4 s = {0.f, 0.f, 0.f, 0.f};
      int row = ii * 16 + x;
      int sw = row & 7;
#pragma unroll
      for (int kk = 0; kk < 4; ++kk) {
        bf16x8 bfv = *(const bf16x8*)(&thT[cur][row * 128 + (((kk * 4 + q) ^ sw) * 8)]);
        s = __builtin_amdgcn_mfma_f32_16x16x32_bf16(af[kk], bfv, s, 0, 0, 0);
      }
#pragma unroll
      for (int r = 0; r < 4; ++r) lsum[r] += __expf(s[r]);
    }
    if (it + 1 < NIT) LSUM_WRITE(cur ^ 1);
    __syncthreads();
    cur ^= 1;
  }
#pragma unroll
  for (int m = 1; m < 16; m <<= 1)
#pragma unroll
    for (int r = 0; r < 4; ++r) lsum[r] += __shfl_xor(lsum[r], m);
  if (x == 0) {
#pragma unroll
    for (int r = 0; r < 4; ++r)
      plsum[((size_t)(b * ISPLIT + iy) << 12) + j0 + w * 16 + 4 * q + r] = lsum[r];
  }
#undef LSUM_LOAD
#undef LSUM_WRITE
}

// ---------------- combine partials -> linv ----------------
__global__ void k_lcomb(const float* __restrict__ plsum, float* __restrict__ linv) {
  int i = blockIdx.x * 256 + threadIdx.x;   // NB*NPOS
  int b = i >> 12, j = i & (NPOS - 1);
  float s = 0.f;
#pragma unroll
  for (int t = 0; t < ISPLIT; ++t) s += plsum[((size_t)(b * ISPLIT + t) << 12) + j];
  linv[i] = 1.0f / s;
}

// ---------------- fold linv into g: gB[cc][p] *= linv[p] ----------------
__global__ void k_scale_g(short* __restrict__ gB, const float* __restrict__ linv) {
  size_t e = ((size_t)blockIdx.x * 256 + threadIdx.x) * 8;
  int b = (int)(e >> 20);
  int p = (int)(e & (NPOS - 1));
  __align__(16) short v[8];
  *(int4*)v = *(const int4*)(gB + e);
  const float* lv = linv + ((size_t)b << 12) + p;
#pragma unroll
  for (int k = 0; k < 8; ++k) v[k] = (short)f2bf(bf2f(v[k]) * lv[k]);
  *(int4*)(gB + e) = *(const int4*)v;
}

// ---------------- attention: omidP[jh][b][cc][i] = sum_{j in half} P*g' -------
__global__ __launch_bounds__(256, 2) void k_attn(
    const short* __restrict__ phiB, const short* __restrict__ thetaB,
    const short* __restrict__ gB, float* __restrict__ omidP) {
  __shared__ short phiT[2][32 * 128];
  __shared__ short gT[2][256 * 32];
  __shared__ short pT[4][16 * 32];
  const int tid = threadIdx.x, lane = tid & 63, w = tid >> 6;
  const int x = lane & 15, q = lane >> 4;
  const int i0 = blockIdx.x * 64, jh = blockIdx.y, b = blockIdx.z;
  const short* phb = phiB + (size_t)b * NPOS * NCI;
  const short* thb = thetaB + (size_t)b * NPOS * NCI;
  const short* gb = gB + (size_t)b * NC * NPOS;
  float* om = omidP + ((size_t)(jh * NB + b)) * NC * NPOS;

  bf16x8 tf[4];
  {
    const short* tr = thb + (size_t)(i0 + w * 16 + x) * NCI;
#pragma unroll
    for (int kk = 0; kk < 4; ++kk) tf[kk] = *(const bf16x8*)(tr + kk * 32 + q * 8);
  }
  f32x4 acc[16];
#pragma unroll
  for (int i = 0; i < 16; ++i) acc[i] = (f32x4){0.f, 0.f, 0.f, 0.f};

  const int sgx = (x & 3) ^ ((x >> 2) & 1);
  int4 rphi[2], rg[4];
  const int NT = 64;
  const int jbase = jh * 64;
#define ATTN_LOAD(jt)                                                          \
  { _Pragma("unroll") for (int r = 0; r < 2; ++r) {                            \
      int s = tid + r * 256; int row = s >> 4, c = s & 15;                     \
      rphi[r] = *(const int4*)(phb + (size_t)((jbase + (jt)) * 32 + row) * NCI + c * 8); } \
    _Pragma("unroll") for (int r = 0; r < 4; ++r) {                            \
      int s = tid + r * 256; int cc = s >> 2, c4 = s & 3;                      \
      rg[r] = *(const int4*)(gb + (size_t)cc * NPOS + (jbase + (jt)) * 32 + c4 * 8); } }
#define ATTN_WRITE(buf)                                                        \
  { _Pragma("unroll") for (int r = 0; r < 2; ++r) {                            \
      int s = tid + r * 256; int row = s >> 4, c = s & 15;                     \
      *(int4*)(&phiT[buf][row * 128 + ((c ^ (row & 7)) * 8)]) = rphi[r]; }     \
    _Pragma("unroll") for (int r = 0; r < 4; ++r) {                            \
      int s = tid + r * 256; int cc = s >> 2, c4 = s & 3;                      \
      int sw = (cc & 3) ^ ((cc >> 2) & 1);                                     \
      *(int4*)(&gT[buf][cc * 32 + ((c4 ^ sw) * 8)]) = rg[r]; } }
  ATTN_LOAD(0); ATTN_WRITE(0); __syncthreads();
  int cur = 0;
  for (int jt = 0; jt < NT; ++jt) {
    if (jt + 1 < NT) ATTN_LOAD(jt + 1);
    {
      const short* PH = &phiT[cur][0];
      const short* GT = &gT[cur][0];
      short* PW = &pT[w][0];
#pragma unroll
      for (int jsub = 0; jsub < 2; ++jsub) {
        f32x4 s = {0.f, 0.f, 0.f, 0.f};
        int row = jsub * 16 + x;
        int sw = row & 7;
#pragma unroll
        for (int kk = 0; kk < 4; ++kk) {
          bf16x8 a = *(const bf16x8*)(PH + row * 128 + (((kk * 4 + q) ^ sw) * 8));
          s = __builtin_amdgcn_mfma_f32_16x16x32_bf16(a, tf[kk], s, 0, 0, 0);
        }
        unsigned short p0 = f2bf(__expf(s[0]));
        unsigned short p1 = f2bf(__expf(s[1]));
        unsigned short p2 = f2bf(__expf(s[2]));
        unsigned short p3 = f2bf(__expf(s[3]));
        unsigned int lo = (unsigned int)p0 | ((unsigned int)p1 << 16);
        unsigned int hi = (unsigned int)p2 | ((unsigned int)p3 << 16);
        int byteoff = (x * 64 + jsub * 32 + q * 8) ^ ((((x >> 1) & 3)) << 4);
        *(uint2*)((char*)PW + byteoff) = make_uint2(lo, hi);
      }
      {
        int c = q ^ ((x >> 1) & 3);
        bf16x8 ap = *(const bf16x8*)((const char*)PW + x * 64 + c * 16);
#pragma unroll
        for (int cf = 0; cf < 16; ++cf) {
          bf16x8 bg = *(const bf16x8*)(GT + (cf * 16 + x) * 32 + ((q ^ sgx) * 8));
          acc[cf] = __builtin_amdgcn_mfma_f32_16x16x32_bf16(ap, bg, acc[cf], 0, 0, 0);
        }
      }
    }
    if (jt + 1 < NT) ATTN_WRITE(cur ^ 1);
    __syncthreads();
    cur ^= 1;
  }
#pragma unroll
  for (int cf = 0; cf < 16; ++cf) {
    size_t o = (size_t)(cf * 16 + x) * NPOS + i0 + w * 16 + 4 * q;
    *reinterpret_cast<f32x4*>(&om[o]) = acc[cf];
  }
#undef ATTN_LOAD
#undef ATTN_WRITE
}

extern "C" void kernel_launch(void* const* d_in, const int* in_sizes, int n_in,
                              void* d_out, int out_size, void* d_ws, size_t ws_size,
                              hipStream_t stream) {
  (void)in_sizes; (void)n_in; (void)out_size; (void)ws_size;
  const float* x0      = (const float*)d_in[0];
  const float* x       = (const float*)d_in[1];
  const float* x_dsm   = (const float*)d_in[2];
  const float* w_phi   = (const float*)d_in[3];
  const float* w_theta = (const float*)d_in[4];
  const float* w_g     = (const float*)d_in[5];
  const float* w_mask  = (const float*)d_in[6];
  float* outp = (float*)d_out;

  short* sp = (short*)d_ws;
  short* wb_phi   = sp; sp += 32768;
  short* wb_theta = sp; sp += 32768;
  short* wb_g     = sp; sp += 131072;
  short* wb_mask  = sp; sp += 131072;
  short* xT   = sp; sp += (size_t)NB * NPOS * NC;
  short* xdT  = sp; sp += (size_t)NB * NPOS * NC;
  short* x0T  = sp; sp += (size_t)NB * NPOS * NC2;
  short* phiB   = sp; sp += (size_t)NB * NPOS * NCI;
  short* thetaB = sp; sp += (size_t)NB * NPOS * NCI;
  short* gBuf   = sp; sp += (size_t)NB * NC * NPOS;
  float* linv = (float*)sp; sp += 2 * (size_t)NB * NPOS;
  float* plsum = (float*)sp;                               // [b][ISPLIT][NPOS]
  float* omidP = (float*)xT;
  short* omidT = phiB;

  k_cast4<<<dim3(1280), 256, 0, stream>>>(w_phi, wb_phi, 32768,
                                          w_theta, wb_theta, 32768,
                                          w_g, wb_g, 131072,
                                          w_mask, wb_mask, 131072);

  k_tcast<<<dim3(64, 4, NB), 256, 0, stream>>>(x, xT, NC, NPOS,
      (size_t)NC * NPOS, (size_t)NPOS * NC);
  k_tcast<<<dim3(64, 4, NB), 256, 0, stream>>>(x_dsm, xdT, NC, NPOS,
      (size_t)NC * NPOS, (size_t)NPOS * NC);
  k_tcast<<<dim3(64, 8, NB), 256, 0, stream>>>(x0, x0T, NC2, NPOS,
      (size_t)NC2 * NPOS, (size_t)NPOS * NC2);

  k_gemm<true, false><<<dim3(64, 2, NB), 256, 0, stream>>>(
      wb_phi, xT, phiB, nullptr, NC, NCI, 0, (size_t)NPOS * NC, (size_t)NPOS * NCI);
  k_gemm<true, false><<<dim3(64, 2, NB), 256, 0, stream>>>(
      wb_theta, xdT, thetaB, nullptr, NC, NCI, 0, (size_t)NPOS * NC, (size_t)NPOS * NCI);
  k_gemm<true, false><<<dim3(4, 64, NB), 256, 0, stream>>>(
      x0T, wb_g, gBuf, nullptr, NC2, NPOS, (size_t)NPOS * NC2, 0, (size_t)NC * NPOS);

  k_lsum<<<dim3(NPOS / 64, ISPLIT, NB), 256, 0, stream>>>(phiB, thetaB, plsum);
  k_lcomb<<<dim3(NB * NPOS / 256), 256, 0, stream>>>(plsum, linv);
  k_scale_g<<<dim3(2048), 256, 0, stream>>>(gBuf, linv);

  k_attn<<<dim3(64, 2, NB), 256, 0, stream>>>(phiB, thetaB, gBuf, omidP);

  k_tcast2<<<dim3(64, 4, NB), 256, 0, stream>>>(omidP, omidP + (size_t)NB * NC * NPOS,
      omidT, NC, NPOS, (size_t)NC * NPOS, (size_t)NPOS * NC);

  k_gemm<false, true><<<dim3(8, 64, NB), 256, 0, stream>>>(
      omidT, wb_mask, outp, x0, NC, NPOS, (size_t)NPOS * NC, 0, (size_t)NC2 * NPOS);
}